// Round 4
// baseline (1634.809 us; speedup 1.0000x reference)
//
#include <hip/hip_runtime.h>

// CG-SENSE: B=4, C=16, H=W=384. fp32. x lives in d_out (float2 == [.,2]).
// FFT-384 = wave-synchronous four-step: in-register FFT-12, per-lane twiddle,
// cross-lane FFT-32 via ds_swizzle. Unscramble through LDS, 13-stride layout:
// natural index w lives at LDS offset offmap(w) = w + w/12 (= 13*(w/12)+w%12).
// Column kernels: 16-column panels, 512 threads, CPITCH=417 (conflict-free),
// mask applied via lane-permuted precomputed maskP (3x float4 per lane, no LDS).

#define Bn 4
#define Cn 16
#define Hn 384
#define Wn 384
#define NPIX (Hn*Wn)
#define TPB 256
#define CTPB 512
#define NCOL 16
#define TOLF 1e-10f
#define NITER 10
#define RED_BLKS 72
#define RPITCH 416   // row-kernel LDS pitch (float2)
#define CPITCH 417   // col-kernel pitch: 834 words % 32 == 2 -> distinct bank pairs

__device__ __forceinline__ float2 cadd(float2 a, float2 b){ return make_float2(a.x+b.x, a.y+b.y); }
__device__ __forceinline__ float2 csub(float2 a, float2 b){ return make_float2(a.x-b.x, a.y-b.y); }
__device__ __forceinline__ float2 cmulf(float2 a, float2 b){
  return make_float2(a.x*b.x - a.y*b.y, a.x*b.y + a.y*b.x);
}

// wave-local LDS fence: DS ops are in-order per wave; write->fence->read within
// a wave is safe without s_barrier.
__device__ __forceinline__ void wave_fence(){ asm volatile("s_waitcnt lgkmcnt(0)" ::: "memory"); }

template<int IMM>
__device__ __forceinline__ float2 shx(float2 v){
  int x = __builtin_amdgcn_ds_swizzle(__float_as_int(v.x), IMM);
  int y = __builtin_amdgcn_ds_swizzle(__float_as_int(v.y), IMM);
  return make_float2(__int_as_float(x), __int_as_float(y));
}

__device__ __forceinline__ int rev5(int x){
  return ((x&1)<<4) | ((x&2)<<2) | (x&4) | ((x&8)>>2) | ((x&16)>>4);
}

__device__ __forceinline__ int offmap(int w){ return w + ((w*683)>>13); }  // w + w/12, w<384

// ---- in-register FFT-12 (natural in, natural out). 12 = 3x4 ----
template<int DIR>
__device__ __forceinline__ void fft12(float2* v)
{
  const float S3 = (DIR<0) ? -0.86602540378443864676f : 0.86602540378443864676f;
  const float sg = (DIR<0) ? -1.f : 1.f;
  float2 t[4][3];
#pragma unroll
  for (int b = 0; b < 4; ++b) {
    float2 a0 = v[b], a1 = v[4+b], a2 = v[8+b];
    float2 s = cadd(a1,a2), d = csub(a1,a2);
    float2 mm = make_float2(a0.x - 0.5f*s.x, a0.y - 0.5f*s.y);
    float2 e  = make_float2(-d.y*S3, d.x*S3);
    t[b][0] = cadd(a0,s);
    t[b][1] = cadd(mm,e);
    t[b][2] = csub(mm,e);
  }
  const float2 w1  = make_float2(0.86602540378443864676f, sg*0.5f);
  const float2 w2  = make_float2(0.5f, sg*0.86602540378443864676f);
  const float2 w3  = make_float2(0.f, sg);
  const float2 w4t = make_float2(-0.5f, sg*0.86602540378443864676f);
  const float2 w6  = make_float2(-1.f, 0.f);
  t[1][1] = cmulf(t[1][1], w1);  t[1][2] = cmulf(t[1][2], w2);
  t[2][1] = cmulf(t[2][1], w2);  t[2][2] = cmulf(t[2][2], w4t);
  t[3][1] = cmulf(t[3][1], w3);  t[3][2] = cmulf(t[3][2], w6);
#pragma unroll
  for (int c = 0; c < 3; ++c) {
    float2 e = cadd(t[0][c], t[2][c]);
    float2 f = csub(t[0][c], t[2][c]);
    float2 g = cadd(t[1][c], t[3][c]);
    float2 h = csub(t[1][c], t[3][c]);
    float2 ih = (DIR<0) ? make_float2(h.y, -h.x) : make_float2(-h.y, h.x);
    v[c]   = cadd(e,g);
    v[c+3] = cadd(f,ih);
    v[c+6] = csub(e,g);
    v[c+9] = csub(f,ih);
  }
}

// ---- cross-lane FFT-32 over lanes (natural in, bit-reversed lane out) ----
template<int DIR>
__device__ __forceinline__ void fft32_lanes(float2* v, int li)
{
  const float c2pi = (DIR<0) ? -6.2831853071795864769f : 6.2831853071795864769f;
  const float sg   = (DIR<0) ? -1.f : 1.f;
  float s, c;
  __sincosf(c2pi*(1.f/32.f)*(float)(li&15), &s, &c); float2 wA = make_float2(c,s);
  __sincosf(c2pi*(1.f/16.f)*(float)(li&7),  &s, &c); float2 wB = make_float2(c,s);
  __sincosf(c2pi*(1.f/ 8.f)*(float)(li&3),  &s, &c); float2 wC = make_float2(c,s);
  bool bA = li & 16, bB = li & 8, bC = li & 4, bD = li & 2, bE = li & 1;
#pragma unroll
  for (int k = 0; k < 12; ++k) {
    float2 a = v[k], o;
    o = shx<0x401F>(a); a = bA ? cmulf(csub(o,a), wA) : cadd(a,o);
    o = shx<0x201F>(a); a = bB ? cmulf(csub(o,a), wB) : cadd(a,o);
    o = shx<0x101F>(a); a = bC ? cmulf(csub(o,a), wC) : cadd(a,o);
    o = shx<0x081F>(a);
    { float2 su = cadd(a,o), d = csub(o,a);
      float2 dw = bE ? make_float2(-sg*d.y, sg*d.x) : d;
      a = bD ? dw : su; }
    o = shx<0x041F>(a); a = bE ? csub(o,a) : cadd(a,o);
    v[k] = a;
  }
}

// Full 384-pt FFT. In: reg k = x[32k+li]. Out: reg k1 = X[k1 + 12*rev5(li)].
template<int DIR>
__device__ __forceinline__ void fft384(float2* v, int li)
{
  fft12<DIR>(v);
  const float c2pi = (DIR<0) ? -6.2831853071795864769f : 6.2831853071795864769f;
  float s, c;
  __sincosf(c2pi*(1.f/384.f)*(float)li, &s, &c);
  float2 W = make_float2(c,s), cw = W;
#pragma unroll
  for (int k = 1; k < 12; ++k) { v[k] = cmulf(v[k], cw); cw = cmulf(cw, W); }
  fft32_lanes<DIR>(v, li);
}

// ---------------- FFT kernels ----------------

// tmp[b,c,h,:] = FFT_w( S[b,c,h,:] * p[b,h,:] )   (unnormalized fwd)
__global__ __launch_bounds__(TPB) void k_row_fwd(
    const float2* __restrict__ p, const float* __restrict__ Sre,
    const float* __restrict__ Sim, float2* __restrict__ tmp)
{
  __shared__ float2 lbuf[8*RPITCH];
  int tid = threadIdx.x;
  int wave = tid>>6, lane = tid&63, sub = lane>>5, li = lane&31;
  int row = wave*2 + sub;
  int tile = blockIdx.x % (Hn/8);
  int bc   = blockIdx.x / (Hn/8);
  int b = bc / Cn;
  int h = tile*8 + row;
  size_t gbase = (size_t)bc*NPIX + (size_t)h*Wn;
  size_t pbase = (size_t)b*NPIX + (size_t)h*Wn;

  float2 v[12];
#pragma unroll
  for (int k = 0; k < 12; ++k) {
    int w = 32*k + li;
    float2 pv = p[pbase + w];
    float sr = Sre[gbase + w], si = Sim[gbase + w];
    v[k] = make_float2(sr*pv.x - si*pv.y, sr*pv.y + si*pv.x);
  }
  fft384<-1>(v, li);
  int m = rev5(li);
  float2* lrow = lbuf + row*RPITCH;
#pragma unroll
  for (int k = 0; k < 12; ++k) lrow[13*m + k] = v[k];
  wave_fence();
#pragma unroll
  for (int k = 0; k < 12; ++k) {
    int w = 32*k + li;
    tmp[gbase + w] = lrow[offmap(w)];
  }
}

// partial[g,b] = sum_{c in group g} conj(S[b,c]) * IFFT_w(tmp[b,c])
template<int CPGt>
__global__ __launch_bounds__(TPB) void k_row_inv_acc(
    const float2* __restrict__ tmp, const float* __restrict__ Sre,
    const float* __restrict__ Sim, float2* __restrict__ partial)
{
  const int GRPt = Cn/CPGt;
  __shared__ float2 lbuf[8*RPITCH];
  int tid = threadIdx.x;
  int wave = tid>>6, lane = tid&63, sub = lane>>5, li = lane&31;
  int row = wave*2 + sub;
  int tile = blockIdx.x % (Hn/8);
  int rest = blockIdx.x / (Hn/8);
  int g = rest % GRPt;
  int b = rest / GRPt;
  int h = tile*8 + row;
  int m = rev5(li);
  float2* lrow = lbuf + row*RPITCH;

  float2 acc[12];
#pragma unroll
  for (int k = 0; k < 12; ++k) acc[k] = make_float2(0.f, 0.f);

  for (int j = 0; j < CPGt; ++j) {
    size_t bc = (size_t)b*Cn + (g*CPGt + j);
    size_t gbase = bc*NPIX + (size_t)h*Wn;
    float2 v[12];
#pragma unroll
    for (int k = 0; k < 12; ++k) v[k] = tmp[gbase + 32*k + li];
    fft384<1>(v, li);
    wave_fence();                       // WAR: prior gather reads drained
#pragma unroll
    for (int k = 0; k < 12; ++k) lrow[13*m + k] = v[k];
    wave_fence();                       // RAW: writes visible before gather
#pragma unroll
    for (int k = 0; k < 12; ++k) {
      int w = 32*k + li;
      float2 u = lrow[offmap(w)];
      float sr = Sre[gbase + w], si = Sim[gbase + w];
      acc[k].x += sr*u.x + si*u.y;
      acc[k].y += sr*u.y - si*u.x;
    }
  }
  size_t pbase = ((size_t)g*Bn + b)*NPIX + (size_t)h*Wn;
#pragma unroll
  for (int k = 0; k < 12; ++k) partial[pbase + 32*k + li] = acc[k];
}

// lane-permuted scaled mask: maskP[((b*Wn+w)*32+li)*12+k] = mask[b][k+12*rev5(li)][w]/NPIX
__global__ __launch_bounds__(TPB) void k_maskp(
    const float* __restrict__ mask, float* __restrict__ maskP)
{
  int idx = blockIdx.x*TPB + threadIdx.x;
  if (idx >= Bn*NPIX) return;
  int k = idx % 12; int t = idx / 12;
  int li = t & 31; t >>= 5;
  int w = t % Wn;  int b = t / Wn;
  maskP[idx] = mask[((size_t)b*Hn + (k + 12*rev5(li)))*Wn + w] * (1.0f/(float)NPIX);
}

// column pass: fwd FFT_h, * maskP, inv FFT_h. 16 columns, 512 threads.
__global__ __launch_bounds__(CTPB) void k_col_full(
    float2* __restrict__ tmp, const float* __restrict__ maskP)
{
  __shared__ float2 dbuf[NCOL*CPITCH];   // 53376 B
  int tid = threadIdx.x;
  int wave = tid>>6, lane = tid&63, sub = lane>>5, li = lane&31;
  int col = wave*2 + sub;
  int tile = blockIdx.x % (Wn/NCOL);
  int bc   = blockIdx.x / (Wn/NCOL);
  int b = bc / Cn;
  int w0 = tile*NCOL;
  size_t tbase = (size_t)bc*NPIX;

  for (int e = tid; e < NCOL*Hn; e += CTPB) {
    int wi = e & (NCOL-1), h = e >> 4;
    dbuf[wi*CPITCH + offmap(h)] = tmp[tbase + (size_t)h*Wn + w0 + wi];
  }
  __syncthreads();

  float2* drow = dbuf + col*CPITCH;
  int w = w0 + col;
  int m = rev5(li);
  float2 v[12];
#pragma unroll
  for (int k = 0; k < 12; ++k) v[k] = drow[offmap(32*k + li)];
  fft384<-1>(v, li);
  const float4* mp4 = (const float4*)(maskP + (((size_t)b*Wn + w)*32 + li)*12);
  float4 m0 = mp4[0], m1 = mp4[1], m2 = mp4[2];
  float mk[12] = {m0.x,m0.y,m0.z,m0.w, m1.x,m1.y,m1.z,m1.w, m2.x,m2.y,m2.z,m2.w};
#pragma unroll
  for (int k = 0; k < 12; ++k) v[k] = make_float2(v[k].x*mk[k], v[k].y*mk[k]);
  wave_fence();
#pragma unroll
  for (int k = 0; k < 12; ++k) drow[13*m + k] = v[k];    // unscramble store
  wave_fence();
#pragma unroll
  for (int k = 0; k < 12; ++k) v[k] = drow[offmap(32*k + li)];  // natural reload
  fft384<1>(v, li);
  wave_fence();
#pragma unroll
  for (int k = 0; k < 12; ++k) drow[13*m + k] = v[k];
  __syncthreads();

  for (int e = tid; e < NCOL*Hn; e += CTPB) {
    int wi = e & (NCOL-1), h = e >> 4;
    tmp[tbase + (size_t)h*Wn + w0 + wi] = dbuf[wi*CPITCH + offmap(h)];
  }
}

// rhs column pass: stage y*mask*(1/384), inverse column FFT only. 16 cols, 512 thr.
__global__ __launch_bounds__(CTPB) void k_col_rhs(
    const float* __restrict__ yre, const float* __restrict__ yim,
    const float* __restrict__ mask, float2* __restrict__ tmp)
{
  __shared__ float2 dbuf[NCOL*CPITCH];
  int tid = threadIdx.x;
  int wave = tid>>6, lane = tid&63, sub = lane>>5, li = lane&31;
  int col = wave*2 + sub;
  int tile = blockIdx.x % (Wn/NCOL);
  int bc   = blockIdx.x / (Wn/NCOL);
  int b = bc / Cn;
  int w0 = tile*NCOL;
  size_t tbase = (size_t)bc*NPIX;
  size_t mbase = (size_t)b*NPIX;

  for (int e = tid; e < NCOL*Hn; e += CTPB) {
    int wi = e & (NCOL-1), h = e >> 4;
    size_t gi = (size_t)h*Wn + w0 + wi;
    float mv = mask[mbase + gi] * (1.0f/384.0f);
    dbuf[wi*CPITCH + offmap(h)] = make_float2(yre[tbase+gi]*mv, yim[tbase+gi]*mv);
  }
  __syncthreads();

  float2* drow = dbuf + col*CPITCH;
  int m = rev5(li);
  float2 v[12];
#pragma unroll
  for (int k = 0; k < 12; ++k) v[k] = drow[offmap(32*k + li)];
  fft384<1>(v, li);
  wave_fence();
#pragma unroll
  for (int k = 0; k < 12; ++k) drow[13*m + k] = v[k];
  __syncthreads();

  for (int e = tid; e < NCOL*Hn; e += CTPB) {
    int wi = e & (NCOL-1), h = e >> 4;
    tmp[tbase + (size_t)h*Wn + w0 + wi] = dbuf[wi*CPITCH + offmap(h)];
  }
}

// ---------------- CG scalar/vector kernels ----------------

__global__ void k_zero_scal(float* __restrict__ scal)
{
  int i = threadIdx.x;
  if (i < 96) scal[i] = 0.0f;
}

__device__ __forceinline__ void block_reduce_atomic(float sum, float* target)
{
  __shared__ float red[TPB];
  red[threadIdx.x] = sum; __syncthreads();
  for (int s = TPB/2; s > 0; s >>= 1) {
    if (threadIdx.x < s) red[threadIdx.x] += red[threadIdx.x + s];
    __syncthreads();
  }
  if (threadIdx.x == 0) unsafeAtomicAdd(target, red[0]);
}

template<int GRPt>
__global__ __launch_bounds__(TPB) void k_rhs_init(
    const float* __restrict__ xre, const float* __restrict__ xim,
    const float* __restrict__ lam, const float2* __restrict__ partial,
    float2* __restrict__ r, float2* __restrict__ p, float2* __restrict__ x,
    float* __restrict__ scal)
{
  int b = blockIdx.y;
  float l = lam[0];
  float sum = 0.0f;
  for (int i = blockIdx.x*TPB + threadIdx.x; i < NPIX; i += RED_BLKS*TPB) {
    size_t gi = (size_t)b*NPIX + i;
    float2 rv = make_float2(l*xre[gi], l*xim[gi]);
#pragma unroll
    for (int g = 0; g < GRPt; ++g) {
      float2 pv = partial[((size_t)g*Bn + b)*NPIX + i];
      rv.x += pv.x; rv.y += pv.y;
    }
    r[gi] = rv; p[gi] = rv;
    x[gi] = make_float2(0.0f, 0.0f);
    sum += rv.x*rv.x + rv.y*rv.y;
  }
  block_reduce_atomic(sum, &scal[b]);
}

template<int GRPt>
__global__ __launch_bounds__(TPB) void k_combine_dot(
    const float2* __restrict__ p, const float* __restrict__ lam,
    const float2* __restrict__ partial, float2* __restrict__ Ap,
    float* __restrict__ slot)
{
  int b = blockIdx.y;
  float l = lam[0];
  float sum = 0.0f;
  for (int i = blockIdx.x*TPB + threadIdx.x; i < NPIX; i += RED_BLKS*TPB) {
    size_t gi = (size_t)b*NPIX + i;
    float2 pv = p[gi];
    float2 av = make_float2(l*pv.x, l*pv.y);
#pragma unroll
    for (int g = 0; g < GRPt; ++g) {
      float2 qv = partial[((size_t)g*Bn + b)*NPIX + i];
      av.x += qv.x; av.y += qv.y;
    }
    Ap[gi] = av;
    sum += pv.x*av.x + pv.y*av.y;
  }
  block_reduce_atomic(sum, &slot[b]);
}

__global__ __launch_bounds__(TPB) void k_upd1(
    float2* __restrict__ x, float2* __restrict__ r,
    const float2* __restrict__ p, const float2* __restrict__ Ap,
    const float* __restrict__ rtr_cur, float* __restrict__ rtr_new,
    const float* __restrict__ pap)
{
  int b = blockIdx.y;
  float rtr = rtr_cur[b];
  bool act = rtr > TOLF;
  float alpha = act ? rtr / pap[b] : 0.0f;
  float sum = 0.0f;
  for (int i = blockIdx.x*TPB + threadIdx.x; i < NPIX; i += RED_BLKS*TPB) {
    size_t gi = (size_t)b*NPIX + i;
    float2 rv = r[gi];
    if (act) {
      float2 pv = p[gi], av = Ap[gi], xv = x[gi];
      xv.x += alpha*pv.x; xv.y += alpha*pv.y;
      rv.x -= alpha*av.x; rv.y -= alpha*av.y;
      x[gi] = xv; r[gi] = rv;
    }
    sum += rv.x*rv.x + rv.y*rv.y;
  }
  block_reduce_atomic(sum, &rtr_new[b]);
}

__global__ __launch_bounds__(TPB) void k_upd2(
    float2* __restrict__ p, const float2* __restrict__ r,
    const float* __restrict__ rtr_cur, const float* __restrict__ rtr_new)
{
  int b = blockIdx.y;
  float rtr = rtr_cur[b];
  if (!(rtr > TOLF)) return;
  float beta = rtr_new[b] / rtr;
  for (int i = blockIdx.x*TPB + threadIdx.x; i < NPIX; i += RED_BLKS*TPB) {
    size_t gi = (size_t)b*NPIX + i;
    float2 rv = r[gi];
    float2 pv = p[gi];
    p[gi] = make_float2(rv.x + beta*pv.x, rv.y + beta*pv.y);
  }
}

// ---------------- launch ----------------

extern "C" void kernel_launch(void* const* d_in, const int* in_sizes, int n_in,
                              void* d_out, int out_size, void* d_ws, size_t ws_size,
                              hipStream_t stream)
{
  const float* lam  = (const float*)d_in[0];
  const float* xre  = (const float*)d_in[1];
  const float* xim  = (const float*)d_in[2];
  const float* yre  = (const float*)d_in[3];
  const float* yim  = (const float*)d_in[4];
  const float* sre  = (const float*)d_in[5];
  const float* sim  = (const float*)d_in[6];
  const float* mask = (const float*)d_in[7];

  const size_t szTmp  = (size_t)Bn*Cn*NPIX*sizeof(float2);
  const size_t szVec  = (size_t)Bn*NPIX*sizeof(float2);
  const size_t szMask = (size_t)Bn*NPIX*sizeof(float);
  const size_t need8  = szTmp + 8*szVec + 3*szVec + 512 + szMask;
  const int GRP = (ws_size >= need8) ? 8 : 4;   // ws_size is fixed -> same path every call

  char* ws = (char*)d_ws;
  float2* tmp  = (float2*)ws;  ws += szTmp;
  float2* part = (float2*)ws;  ws += (size_t)GRP*szVec;
  float2* r    = (float2*)ws;  ws += szVec;
  float2* p    = (float2*)ws;  ws += szVec;
  float2* Ap   = (float2*)ws;  ws += szVec;
  float*  scal = (float*)ws;   ws += 512;   // rTr[11][B] at [0..43], pAp[10][B] at [44..83]
  float*  mskP = (float*)ws;
  float2* x    = (float2*)d_out;

  dim3 blk(TPB);
  dim3 rg(RED_BLKS, Bn);
  int grid_row = Bn*Cn*(Hn/8);       // 3072
  int grid_col = Bn*Cn*(Wn/NCOL);    // 1536
  int grid_inv = Bn*GRP*(Hn/8);      // 1536 (GRP=8) / 768 (GRP=4)

  k_zero_scal<<<1, 128, 0, stream>>>(scal);
  k_maskp<<<(Bn*NPIX + TPB-1)/TPB, blk, 0, stream>>>(mask, mskP);

  // ---- rhs = AH(y) + lambda*x ----
  k_col_rhs<<<grid_col, CTPB, 0, stream>>>(yre, yim, mask, tmp);
  if (GRP == 8) {
    k_row_inv_acc<2><<<grid_inv, blk, 0, stream>>>(tmp, sre, sim, part);
    k_rhs_init<8><<<rg, blk, 0, stream>>>(xre, xim, lam, part, r, p, x, scal);
  } else {
    k_row_inv_acc<4><<<grid_inv, blk, 0, stream>>>(tmp, sre, sim, part);
    k_rhs_init<4><<<rg, blk, 0, stream>>>(xre, xim, lam, part, r, p, x, scal);
  }

  for (int it = 0; it < NITER; ++it) {
    k_row_fwd<<<grid_row, blk, 0, stream>>>(p, sre, sim, tmp);
    k_col_full<<<grid_col, CTPB, 0, stream>>>(tmp, mskP);
    if (GRP == 8) {
      k_row_inv_acc<2><<<grid_inv, blk, 0, stream>>>(tmp, sre, sim, part);
      k_combine_dot<8><<<rg, blk, 0, stream>>>(p, lam, part, Ap, scal + 44 + it*Bn);
    } else {
      k_row_inv_acc<4><<<grid_inv, blk, 0, stream>>>(tmp, sre, sim, part);
      k_combine_dot<4><<<rg, blk, 0, stream>>>(p, lam, part, Ap, scal + 44 + it*Bn);
    }
    k_upd1<<<rg, blk, 0, stream>>>(x, r, p, Ap, scal + it*Bn, scal + (it+1)*Bn, scal + 44 + it*Bn);
    if (it < NITER-1)
      k_upd2<<<rg, blk, 0, stream>>>(p, r, scal + it*Bn, scal + (it+1)*Bn);
  }
}